// Round 10
// baseline (115.557 us; speedup 1.0000x reference)
//
#include <hip/hip_runtime.h>

// FinePreprocess, MFMA version, plane-tiled bf16 feature maps.
// B=2, D_F=128, Hf=240, Wf=320, L=4800 (60x80), W=5, stride=4, D_C=256, M=3000.
//
//  transpose: feat [b][c][h][w] f32 -> tmap [b][c8][pix][8ch] bf16.
//             r4 structure (measured best: 62-66us) + NON-TEMPORAL tmap stores.
//             Cross-round invariant: every transpose variant's replay FETCH
//             ~= 77MB at 64-80us regardless of access pattern => the 155MB/call
//             of write streams (tmap+out) evict the 157MB input from the 256MB
//             L3 (working set 323MB). NT writes stop the eviction so the input
//             stays L3-resident across graph replays.
//  prep:      CW[256][128] = down_W^T @ W2^T (f32), cbias[128], W1bf[n][c] bf16
//  t2:        t2[m][o] = c_row[m] @ CW + cbias   (f32, w-invariant term)
//  fine:      out[m][p][o] = sum_c win[p][c]*W1[o][c] + t2[m][o] via mfma 16x16x32.
//             A global->reg in frag layout from tmap; B in XOR-swizzled LDS;
//             out stores non-temporal (write-once, never re-read).

#define HF 240
#define WF 320
#define HWF (HF * WF)
#define LPOS 4800

typedef short short8 __attribute__((ext_vector_type(8)));
typedef unsigned short ushort8 __attribute__((ext_vector_type(8)));
typedef float f32x4 __attribute__((ext_vector_type(4)));

__device__ __forceinline__ unsigned short f2bf(float x) {
  union { float f; unsigned u; } v; v.f = x;
  unsigned r = v.u + 0x7FFF + ((v.u >> 16) & 1);  // RNE
  return (unsigned short)(r >> 16);
}

// ---------------- transpose + bf16 convert (LDS-free, NT stores) ----------------
// grid (300, 16, 4): x = 256-pixel tile, y = c8 plane (8 channels), z = map*2+b.
__global__ __launch_bounds__(256) void transpose_kernel(
    const float* __restrict__ f0, const float* __restrict__ f1,
    unsigned short* __restrict__ t0, unsigned short* __restrict__ t1) {
  const int t = threadIdx.x;
  const int px = blockIdx.x * 256 + t;
  const int c8 = blockIdx.y;
  const int mb = blockIdx.z;  // map*2 + b
  const float* src = ((mb >> 1) ? f1 : f0)
                   + ((size_t)(mb & 1) * 128 + (size_t)c8 * 8) * HWF + px;
  unsigned short* dst = ((mb >> 1) ? t1 : t0)
                      + (((size_t)(mb & 1) * 16 + (size_t)c8) * HWF + px) * 8;

  float v[8];
  #pragma unroll
  for (int j = 0; j < 8; ++j) v[j] = src[(size_t)j * HWF];
  ushort8 u;
  #pragma unroll
  for (int j = 0; j < 8; ++j) u[j] = f2bf(v[j]);
  __builtin_nontemporal_store(u, (ushort8*)dst);  // don't evict input from L3
}

// ---------------- prep: CW, cbias, W1bf ----------------
__global__ __launch_bounds__(256) void prep_kernel(
    const float* __restrict__ down_W, const float* __restrict__ down_b,
    const float* __restrict__ merge_W, const float* __restrict__ merge_b,
    float* __restrict__ CW, float* __restrict__ cbias,
    unsigned short* __restrict__ W1bf) {
  int idx = blockIdx.x * 256 + threadIdx.x;
  if (idx < 32768) {
    int k = idx >> 7, o = idx & 127;  // CW[k][o] = sum_t down_W[t][k]*merge_W[o][128+t]
    float s = 0.f;
    #pragma unroll 4
    for (int t = 0; t < 128; ++t)
      s += down_W[t * 256 + k] * merge_W[o * 256 + 128 + t];
    CW[idx] = s;
  } else if (idx < 49152) {
    int i2 = idx - 32768;
    int n = i2 >> 7, c = i2 & 127;
    W1bf[i2] = f2bf(merge_W[n * 256 + c]);  // W1bf[n][c]
  } else if (idx < 49280) {
    int o = idx - 49152;
    float s = merge_b[o];
    #pragma unroll 4
    for (int t = 0; t < 128; ++t)
      s += down_b[t] * merge_W[o * 256 + 128 + t];
    cbias[o] = s;
  }
}

// ---------------- t2: coarse path (f32, proven) ----------------
__global__ __launch_bounds__(256) void t2_kernel(
    const float* __restrict__ c0, const float* __restrict__ c1,
    const int* __restrict__ b_ids, const int* __restrict__ i_ids,
    const int* __restrict__ j_ids,
    const float* __restrict__ CW, const float* __restrict__ cbias,
    float* __restrict__ t2, int M) {
  __shared__ float crow[8][256];
  const int t = threadIdx.x;
  const int m0 = blockIdx.x * 8;
  const int M2 = 2 * M;
  #pragma unroll
  for (int it = 0; it < 8; ++it) {
    int m = m0 + it;
    float v = 0.f;
    if (m < M2) {
      int b, pos;
      const float* src;
      if (m < M) { b = b_ids[m]; pos = i_ids[m]; src = c0; }
      else       { b = b_ids[m - M]; pos = j_ids[m - M]; src = c1; }
      v = src[((size_t)b * LPOS + pos) * 256 + t];
    }
    crow[it][t] = v;
  }
  __syncthreads();
  const int o = t & 127, half = t >> 7;
  const int r0 = half * 4;
  float a0 = 0.f, a1 = 0.f, a2 = 0.f, a3 = 0.f;
  #pragma unroll 4
  for (int k = 0; k < 256; ++k) {
    float wv = CW[k * 128 + o];
    a0 += crow[r0 + 0][k] * wv;
    a1 += crow[r0 + 1][k] * wv;
    a2 += crow[r0 + 2][k] * wv;
    a3 += crow[r0 + 3][k] * wv;
  }
  const float cb = cbias[o];
  if (m0 + r0 + 0 < M2) t2[(size_t)(m0 + r0 + 0) * 128 + o] = a0 + cb;
  if (m0 + r0 + 1 < M2) t2[(size_t)(m0 + r0 + 1) * 128 + o] = a1 + cb;
  if (m0 + r0 + 2 < M2) t2[(size_t)(m0 + r0 + 2) * 128 + o] = a2 + cb;
  if (m0 + r0 + 3 < M2) t2[(size_t)(m0 + r0 + 3) * 128 + o] = a3 + cb;
}

// ---------------- fine: MFMA ----------------
// 4 waves/block, 1 m per wave. A global->reg in frag layout; B in swizzled LDS.
__global__ __launch_bounds__(256) void fine_mfma_kernel(
    const unsigned short* __restrict__ t0, const unsigned short* __restrict__ t1,
    const int* __restrict__ b_ids, const int* __restrict__ i_ids,
    const int* __restrict__ j_ids,
    const unsigned short* __restrict__ W1bf, const float* __restrict__ t2,
    float* __restrict__ out, int M) {
  __shared__ unsigned short Bl[128 * 128];  // swizzled [n][c] bf16, 32KB
  const int t = threadIdx.x;

  // stage B: rows n of W1bf, 16B chunks, XOR swizzle kb ^ ((n&7)<<4)
  #pragma unroll
  for (int it = 0; it < 8; ++it) {
    int q = it * 256 + t;
    int n = q >> 4;
    int kb16 = (q & 15) * 16;
    short8 v = *(const short8*)&W1bf[n * 128 + (q & 15) * 8];
    int dstB = n * 256 + (kb16 ^ ((n & 7) << 4));
    *(short8*)((char*)Bl + dstB) = v;
  }

  const int wid = t >> 6, lane = t & 63;
  const int lr = lane & 15, lg = lane >> 4;
  const int m = blockIdx.x * 4 + wid;
  const int M2 = 2 * M;
  const bool active = (m < M2);

  // A-fragments: lane holds window[p = mt*16+lr][k = kk*32 + lg*8 + 0..7]
  // tmap layout [b][c8][pix][8]: channels kk*32+lg*8.. are plane c8=kk*4+lg.
  short8 a[2][4];
  short8 az = {};
  if (active) {
    int b, pos;
    const unsigned short* tm;
    if (m < M) { b = b_ids[m]; pos = i_ids[m]; tm = t0; }
    else       { int mm = m - M; b = b_ids[mm]; pos = j_ids[mm]; tm = t1; }
    tm += (size_t)b * 16 * HWF * 8;
    int hc = pos / 80, wc = pos - hc * 80;
    int h0 = hc * 4 - 2, w0 = wc * 4 - 2;
    #pragma unroll
    for (int mt = 0; mt < 2; ++mt) {
      int p = mt * 16 + lr;
      int pr = p / 5;
      int hh = h0 + pr, ww = w0 + (p - pr * 5);
      bool valid = (p < 25) && ((unsigned)hh < (unsigned)HF) && ((unsigned)ww < (unsigned)WF);
      int px = valid ? (hh * WF + ww) : 0;
      #pragma unroll
      for (int kk = 0; kk < 4; ++kk) {
        const short8* ap =
            (const short8*)(tm + (((size_t)(kk * 4 + lg) * HWF + px) << 3));
        a[mt][kk] = valid ? *ap : az;
      }
    }
  } else {
    #pragma unroll
    for (int mt = 0; mt < 2; ++mt)
      #pragma unroll
      for (int kk = 0; kk < 4; ++kk) a[mt][kk] = az;
  }

  __syncthreads();
  if (!active) return;

  f32x4 acc[2][8];
  #pragma unroll
  for (int mt = 0; mt < 2; ++mt)
    #pragma unroll
    for (int nt = 0; nt < 8; ++nt) {
      f32x4 z = {0.f, 0.f, 0.f, 0.f};
      acc[mt][nt] = z;
    }

  #pragma unroll
  for (int nt = 0; nt < 8; ++nt) {
    int n = nt * 16 + lr;
    int kbase = n * 256;
    int sw = (n & 7) << 4;
    short8 bfr[4];
    #pragma unroll
    for (int kk = 0; kk < 4; ++kk) {
      int kb = (kk * 64 + lg * 16) ^ sw;
      bfr[kk] = *(const short8*)((const char*)Bl + kbase + kb);
    }
    #pragma unroll
    for (int kk = 0; kk < 4; ++kk) {
      acc[0][nt] = __builtin_amdgcn_mfma_f32_16x16x32_bf16(a[0][kk], bfr[kk], acc[0][nt], 0, 0, 0);
      acc[1][nt] = __builtin_amdgcn_mfma_f32_16x16x32_bf16(a[1][kk], bfr[kk], acc[1][nt], 0, 0, 0);
    }
  }

  // epilogue: D row = mt*16 + lg*4 + j (skip rows >= 25), col = nt*16 + lr.
  // Non-temporal: out is write-once, never re-read.
  const float* t2row = t2 + (size_t)m * 128;
  float* orow = out + (size_t)m * 25 * 128;
  #pragma unroll
  for (int nt = 0; nt < 8; ++nt) {
    int o = nt * 16 + lr;
    float tv = t2row[o];
    #pragma unroll
    for (int mt = 0; mt < 2; ++mt) {
      #pragma unroll
      for (int j = 0; j < 4; ++j) {
        int r = mt * 16 + lg * 4 + j;
        if (r < 25)
          __builtin_nontemporal_store(acc[mt][nt][j] + tv, &orow[r * 128 + o]);
      }
    }
  }
}

extern "C" void kernel_launch(void* const* d_in, const int* in_sizes, int n_in,
                              void* d_out, int out_size, void* d_ws, size_t ws_size,
                              hipStream_t stream) {
  const float* f0      = (const float*)d_in[0];
  const float* f1      = (const float*)d_in[1];
  const float* c0      = (const float*)d_in[2];
  const float* c1      = (const float*)d_in[3];
  const int*   b_ids   = (const int*)d_in[6];
  const int*   i_ids   = (const int*)d_in[7];
  const int*   j_ids   = (const int*)d_in[8];
  const float* down_W  = (const float*)d_in[9];
  const float* down_b  = (const float*)d_in[10];
  const float* merge_W = (const float*)d_in[11];
  const float* merge_b = (const float*)d_in[12];
  const int M = in_sizes[6];
  const int M2 = 2 * M;

  char* wsb = (char*)d_ws;
  float* CW    = (float*)wsb;                 // 131072 B
  float* cbias = (float*)(wsb + 131072);      // 512 B
  float* t2    = (float*)(wsb + 131584);      // 2M*128*4 B
  size_t off = 131584 + (size_t)M2 * 128 * 4;
  off = (off + 255) & ~(size_t)255;
  unsigned short* W1bf = (unsigned short*)(wsb + off);  // 32768 B
  off += 32768;
  unsigned short* t0 = (unsigned short*)(wsb + off);    // 2*16*HWF*8*2 B
  off += (size_t)2 * 16 * HWF * 8 * 2;
  unsigned short* t1 = (unsigned short*)(wsb + off);

  transpose_kernel<<<dim3(300, 16, 4), 256, 0, stream>>>(f0, f1, t0, t1);
  prep_kernel<<<193, 256, 0, stream>>>(down_W, down_b, merge_W, merge_b,
                                       CW, cbias, W1bf);
  t2_kernel<<<(M2 + 7) / 8, 256, 0, stream>>>(c0, c1, b_ids, i_ids, j_ids,
                                              CW, cbias, t2, M);
  fine_mfma_kernel<<<(M2 + 3) / 4, 256, 0, stream>>>(t0, t1, b_ids, i_ids, j_ids,
                                                     W1bf, t2, (float*)d_out, M);
}

// Round 11
// 98.916 us; speedup vs baseline: 1.1682x; 1.1682x over previous
//
#include <hip/hip_runtime.h>

// FinePreprocess. B=2, D_F=128, Hf=240, Wf=320, L=4800 (60x80), W=5, stride=4,
// D_C=256, M=3000.
//
//  prep:  CW[256][128] = down_W^T @ W2^T (f32), cbias[128], W1bf[n][c] bf16
//  work:  FUSED kernel, blockIdx split (no inter-block deps):
//           bid < 750:  t2[m][o] = c_row[m] @ CW + cbias (fills CU bubbles)
//           bid >= 750: transpose feat f32 NCHW -> tmap [b][c8][pix][8] bf16
//                       (r4/r10 structure, measured wall ~63us, NT stores).
//         Rationale: same-stream kernels serialize and events are banned under
//         graph capture, so concurrency must come from a single dispatch.
//  fine:  out[m][p][o] = sum_c win[p][c]*W1[o][c] + t2[m][o] via mfma 16x16x32.
//         8 m per block (2 per wave, sequential) -> half the blocks, half the
//         B-staging traffic and barriers of the 4-m version.

#define HF 240
#define WF 320
#define HWF (HF * WF)
#define LPOS 4800

typedef short short8 __attribute__((ext_vector_type(8)));
typedef unsigned short ushort8 __attribute__((ext_vector_type(8)));
typedef float f32x4 __attribute__((ext_vector_type(4)));

__device__ __forceinline__ unsigned short f2bf(float x) {
  union { float f; unsigned u; } v; v.f = x;
  unsigned r = v.u + 0x7FFF + ((v.u >> 16) & 1);  // RNE
  return (unsigned short)(r >> 16);
}

// ---------------- prep: CW, cbias, W1bf ----------------
__global__ __launch_bounds__(256) void prep_kernel(
    const float* __restrict__ down_W, const float* __restrict__ down_b,
    const float* __restrict__ merge_W, const float* __restrict__ merge_b,
    float* __restrict__ CW, float* __restrict__ cbias,
    unsigned short* __restrict__ W1bf) {
  int idx = blockIdx.x * 256 + threadIdx.x;
  if (idx < 32768) {
    int k = idx >> 7, o = idx & 127;  // CW[k][o] = sum_t down_W[t][k]*merge_W[o][128+t]
    float s = 0.f;
    #pragma unroll 4
    for (int t = 0; t < 128; ++t)
      s += down_W[t * 256 + k] * merge_W[o * 256 + 128 + t];
    CW[idx] = s;
  } else if (idx < 49152) {
    int i2 = idx - 32768;
    int n = i2 >> 7, c = i2 & 127;
    W1bf[i2] = f2bf(merge_W[n * 256 + c]);  // W1bf[n][c]
  } else if (idx < 49280) {
    int o = idx - 49152;
    float s = merge_b[o];
    #pragma unroll 4
    for (int t = 0; t < 128; ++t)
      s += down_b[t] * merge_W[o * 256 + 128 + t];
    cbias[o] = s;
  }
}

// ---------------- fused work kernel: t2 (low bids) + transpose ----------------
// grid: T2B + 19200 blocks. T2B = ceil(2M/8).
__global__ __launch_bounds__(256) void work_kernel(
    const float* __restrict__ f0, const float* __restrict__ f1,
    unsigned short* __restrict__ t0, unsigned short* __restrict__ t1,
    const float* __restrict__ c0, const float* __restrict__ c1,
    const int* __restrict__ b_ids, const int* __restrict__ i_ids,
    const int* __restrict__ j_ids,
    const float* __restrict__ CW, const float* __restrict__ cbias,
    float* __restrict__ t2, int M, int T2B) {
  __shared__ float crow[8][256];
  const int t = threadIdx.x;
  const int bid = blockIdx.x;

  if (bid >= T2B) {
    // ---- transpose part (r10 structure, NT stores) ----
    const int q = bid - T2B;
    const int bx = q % 300;
    const int c8 = (q / 300) & 15;
    const int mb = q / 4800;  // map*2 + b
    const int px = bx * 256 + t;
    const float* src = ((mb >> 1) ? f1 : f0)
                     + ((size_t)(mb & 1) * 128 + (size_t)c8 * 8) * HWF + px;
    unsigned short* dst = ((mb >> 1) ? t1 : t0)
                        + (((size_t)(mb & 1) * 16 + (size_t)c8) * HWF + px) * 8;
    float v[8];
    #pragma unroll
    for (int j = 0; j < 8; ++j) v[j] = src[(size_t)j * HWF];
    ushort8 u;
    #pragma unroll
    for (int j = 0; j < 8; ++j) u[j] = f2bf(v[j]);
    __builtin_nontemporal_store(u, (ushort8*)dst);
    return;
  }

  // ---- t2 part ----
  const int m0 = bid * 8;
  const int M2 = 2 * M;
  #pragma unroll
  for (int it = 0; it < 8; ++it) {
    int m = m0 + it;
    float v = 0.f;
    if (m < M2) {
      int b, pos;
      const float* src;
      if (m < M) { b = b_ids[m]; pos = i_ids[m]; src = c0; }
      else       { b = b_ids[m - M]; pos = j_ids[m - M]; src = c1; }
      v = src[((size_t)b * LPOS + pos) * 256 + t];
    }
    crow[it][t] = v;
  }
  __syncthreads();
  const int o = t & 127, half = t >> 7;
  const int r0 = half * 4;
  float a0 = 0.f, a1 = 0.f, a2 = 0.f, a3 = 0.f;
  #pragma unroll 4
  for (int k = 0; k < 256; ++k) {
    float wv = CW[k * 128 + o];
    a0 += crow[r0 + 0][k] * wv;
    a1 += crow[r0 + 1][k] * wv;
    a2 += crow[r0 + 2][k] * wv;
    a3 += crow[r0 + 3][k] * wv;
  }
  const float cb = cbias[o];
  if (m0 + r0 + 0 < M2) t2[(size_t)(m0 + r0 + 0) * 128 + o] = a0 + cb;
  if (m0 + r0 + 1 < M2) t2[(size_t)(m0 + r0 + 1) * 128 + o] = a1 + cb;
  if (m0 + r0 + 2 < M2) t2[(size_t)(m0 + r0 + 2) * 128 + o] = a2 + cb;
  if (m0 + r0 + 3 < M2) t2[(size_t)(m0 + r0 + 3) * 128 + o] = a3 + cb;
}

// ---------------- fine: MFMA, 8 m per block ----------------
// 4 waves/block; each wave does 2 sequential m's (Bl staged once).
__global__ __launch_bounds__(256) void fine_mfma_kernel(
    const unsigned short* __restrict__ t0, const unsigned short* __restrict__ t1,
    const int* __restrict__ b_ids, const int* __restrict__ i_ids,
    const int* __restrict__ j_ids,
    const unsigned short* __restrict__ W1bf, const float* __restrict__ t2,
    float* __restrict__ out, int M) {
  __shared__ unsigned short Bl[128 * 128];  // swizzled [n][c] bf16, 32KB
  const int t = threadIdx.x;

  // stage B: rows n of W1bf, 16B chunks, XOR swizzle kb ^ ((n&7)<<4)
  #pragma unroll
  for (int it = 0; it < 8; ++it) {
    int q = it * 256 + t;
    int n = q >> 4;
    int kb16 = (q & 15) * 16;
    short8 v = *(const short8*)&W1bf[n * 128 + (q & 15) * 8];
    int dstB = n * 256 + (kb16 ^ ((n & 7) << 4));
    *(short8*)((char*)Bl + dstB) = v;
  }
  __syncthreads();

  const int wid = t >> 6, lane = t & 63;
  const int lr = lane & 15, lg = lane >> 4;
  const int M2 = 2 * M;

  #pragma unroll 1
  for (int im = 0; im < 2; ++im) {
    const int m = blockIdx.x * 8 + im * 4 + wid;
    if (m >= M2) continue;

    // A-fragments: lane holds window[p = mt*16+lr][k = kk*32 + lg*8 + 0..7]
    // tmap layout [b][c8][pix][8]: channels kk*32+lg*8.. are plane c8=kk*4+lg.
    short8 a[2][4];
    short8 az = {};
    {
      int b, pos;
      const unsigned short* tm;
      if (m < M) { b = b_ids[m]; pos = i_ids[m]; tm = t0; }
      else       { int mm = m - M; b = b_ids[mm]; pos = j_ids[mm]; tm = t1; }
      tm += (size_t)b * 16 * HWF * 8;
      int hc = pos / 80, wc = pos - hc * 80;
      int h0 = hc * 4 - 2, w0 = wc * 4 - 2;
      #pragma unroll
      for (int mt = 0; mt < 2; ++mt) {
        int p = mt * 16 + lr;
        int pr = p / 5;
        int hh = h0 + pr, ww = w0 + (p - pr * 5);
        bool valid = (p < 25) && ((unsigned)hh < (unsigned)HF) && ((unsigned)ww < (unsigned)WF);
        int px = valid ? (hh * WF + ww) : 0;
        #pragma unroll
        for (int kk = 0; kk < 4; ++kk) {
          const short8* ap =
              (const short8*)(tm + (((size_t)(kk * 4 + lg) * HWF + px) << 3));
          a[mt][kk] = valid ? *ap : az;
        }
      }
    }

    f32x4 acc[2][8];
    #pragma unroll
    for (int mt = 0; mt < 2; ++mt)
      #pragma unroll
      for (int nt = 0; nt < 8; ++nt) {
        f32x4 z = {0.f, 0.f, 0.f, 0.f};
        acc[mt][nt] = z;
      }

    #pragma unroll
    for (int nt = 0; nt < 8; ++nt) {
      int n = nt * 16 + lr;
      int kbase = n * 256;
      int sw = (n & 7) << 4;
      short8 bfr[4];
      #pragma unroll
      for (int kk = 0; kk < 4; ++kk) {
        int kb = (kk * 64 + lg * 16) ^ sw;
        bfr[kk] = *(const short8*)((const char*)Bl + kbase + kb);
      }
      #pragma unroll
      for (int kk = 0; kk < 4; ++kk) {
        acc[0][nt] = __builtin_amdgcn_mfma_f32_16x16x32_bf16(a[0][kk], bfr[kk], acc[0][nt], 0, 0, 0);
        acc[1][nt] = __builtin_amdgcn_mfma_f32_16x16x32_bf16(a[1][kk], bfr[kk], acc[1][nt], 0, 0, 0);
      }
    }

    // epilogue: D row = mt*16 + lg*4 + j (skip rows >= 25), col = nt*16 + lr
    const float* t2row = t2 + (size_t)m * 128;
    float* orow = out + (size_t)m * 25 * 128;
    #pragma unroll
    for (int nt = 0; nt < 8; ++nt) {
      int o = nt * 16 + lr;
      float tv = t2row[o];
      #pragma unroll
      for (int mt = 0; mt < 2; ++mt) {
        #pragma unroll
        for (int j = 0; j < 4; ++j) {
          int r = mt * 16 + lg * 4 + j;
          if (r < 25) orow[r * 128 + o] = acc[mt][nt][j] + tv;
        }
      }
    }
  }
}

extern "C" void kernel_launch(void* const* d_in, const int* in_sizes, int n_in,
                              void* d_out, int out_size, void* d_ws, size_t ws_size,
                              hipStream_t stream) {
  const float* f0      = (const float*)d_in[0];
  const float* f1      = (const float*)d_in[1];
  const float* c0      = (const float*)d_in[2];
  const float* c1      = (const float*)d_in[3];
  const int*   b_ids   = (const int*)d_in[6];
  const int*   i_ids   = (const int*)d_in[7];
  const int*   j_ids   = (const int*)d_in[8];
  const float* down_W  = (const float*)d_in[9];
  const float* down_b  = (const float*)d_in[10];
  const float* merge_W = (const float*)d_in[11];
  const float* merge_b = (const float*)d_in[12];
  const int M = in_sizes[6];
  const int M2 = 2 * M;
  const int T2B = (M2 + 7) / 8;

  char* wsb = (char*)d_ws;
  float* CW    = (float*)wsb;                 // 131072 B
  float* cbias = (float*)(wsb + 131072);      // 512 B
  float* t2    = (float*)(wsb + 131584);      // 2M*128*4 B
  size_t off = 131584 + (size_t)M2 * 128 * 4;
  off = (off + 255) & ~(size_t)255;
  unsigned short* W1bf = (unsigned short*)(wsb + off);  // 32768 B
  off += 32768;
  unsigned short* t0 = (unsigned short*)(wsb + off);    // 2*16*HWF*8*2 B
  off += (size_t)2 * 16 * HWF * 8 * 2;
  unsigned short* t1 = (unsigned short*)(wsb + off);

  prep_kernel<<<193, 256, 0, stream>>>(down_W, down_b, merge_W, merge_b,
                                       CW, cbias, W1bf);
  work_kernel<<<T2B + 19200, 256, 0, stream>>>(f0, f1, t0, t1, c0, c1,
                                               b_ids, i_ids, j_ids,
                                               CW, cbias, t2, M, T2B);
  fine_mfma_kernel<<<(M2 + 7) / 8, 256, 0, stream>>>(t0, t1, b_ids, i_ids, j_ids,
                                                     W1bf, t2, (float*)d_out, M);
}